// Round 13
// baseline (1143.305 us; speedup 1.0000x reference)
//
#include <hip/hip_runtime.h>
#include <math.h>

#define HID  128
#define EDIM 4

typedef unsigned short u16;
typedef u16    us8   __attribute__((ext_vector_type(8)));
typedef __bf16 bf16x8 __attribute__((ext_vector_type(8)));
typedef float  f32x4 __attribute__((ext_vector_type(4)));

// silu via hw rcp: v_rcp_f32 (~1 ulp) instead of IEEE div (10+ inst w/o fast-math)
__device__ __forceinline__ float silu_f(float v) {
    return v * __builtin_amdgcn_rcpf(1.0f + __expf(-v));
}
__device__ __forceinline__ u16 f2bf(float f) {   // RNE fp32->bf16 (cold paths)
    unsigned u = __float_as_uint(f);
    unsigned r = u + 0x7fffu + ((u >> 16) & 1u);
    return (u16)(r >> 16);
}
__device__ __forceinline__ u16 f2bf_fast(float f) {  // round-half-up, 2 ops (hot)
    return (u16)((__float_as_uint(f) + 0x8000u) >> 16);
}
__device__ __forceinline__ float bf2f(u16 s) {
    return __uint_as_float(((unsigned)s) << 16);
}
__device__ __forceinline__ bf16x8 as_bf(us8 v) {
    return __builtin_bit_cast(bf16x8, v);
}

// ---------------- fused setup: weight swizzle + zero-fills ------------------
__device__ __forceinline__ void wfrag_one(const float* __restrict__ w,
        u16* __restrict__ out, int KT, int K, int idx) {
    int lane = idx & 63;
    int f    = (idx >> 6) % (KT * 8);
    int l    = idx / (64 * KT * 8);
    int kt = f >> 3, nt = f & 7;
    int n  = nt * 16 + (lane & 15);
    int k0 = kt * 32 + ((lane >> 4) * 8);
    us8 v;
    #pragma unroll
    for (int j = 0; j < 8; ++j) {
        int k = k0 + j;
        v[j] = (k < K) ? f2bf(w[((size_t)l * K + k) * HID + n]) : (u16)0;
    }
    *(us8*)&out[((size_t)(l * KT * 8 + f) * 64 + lane) * 8] = v;
}

#define T1 (4 * 9 * 8 * 64)
#define T2 (4 * 4 * 8 * 64)
#define T3 (4 * 8 * 8 * 64)

__global__ __launch_bounds__(256) void setup_kernel(
        const float* __restrict__ ew1, const float* __restrict__ ew2,
        const float* __restrict__ nw,
        u16* __restrict__ w1f, u16* __restrict__ w2f, u16* __restrict__ nwf,
        int* __restrict__ cnt, int* __restrict__ cursor,
        float* __restrict__ sums, float* __restrict__ cnts_g, int N, int G) {
    int idx = blockIdx.x * 256 + threadIdx.x;
    if (idx < T1) { wfrag_one(ew1, w1f, 9, 2 * HID + EDIM, idx); return; }
    idx -= T1;
    if (idx < T2) { wfrag_one(ew2, w2f, 4, HID, idx); return; }
    idx -= T2;
    if (idx < T3) { wfrag_one(nw, nwf, 8, 2 * HID, idx); return; }
    idx -= T3;
    if (idx < N) { cnt[idx] = 0; return; }
    idx -= N;
    if (idx < N) { cursor[idx] = 0; return; }
    idx -= N;
    if (idx < G * HID) { sums[idx] = 0.f; return; }
    idx -= G * HID;
    if (idx < G) { cnts_g[idx] = 0.f; return; }
}

// ---------------- CSR build: hist -> scan -> scatter ------------------------
__global__ __launch_bounds__(256) void hist_kernel(const int* __restrict__ dst,
        int* __restrict__ cnt, int E) {
    int e = blockIdx.x * 256 + threadIdx.x;
    if (e < E) atomicAdd(&cnt[dst[e]], 1);
}

__global__ __launch_bounds__(1024) void scan_kernel(const int* __restrict__ cnt,
        int* __restrict__ rowptr, int n) {
    __shared__ int s[1024];
    const int t = threadIdx.x;
    const int chunk = (n + 1023) >> 10;
    int lo = t * chunk, hi = lo + chunk;
    if (lo > n) lo = n;
    if (hi > n) hi = n;
    int sum = 0;
    for (int i = lo; i < hi; ++i) sum += cnt[i];
    s[t] = sum;
    __syncthreads();
    for (int off = 1; off < 1024; off <<= 1) {
        int v = (t >= off) ? s[t - off] : 0;
        __syncthreads();
        s[t] += v;
        __syncthreads();
    }
    int run = s[t] - sum;
    for (int i = lo; i < hi; ++i) { rowptr[i] = run; run += cnt[i]; }
    if (t == 1023) rowptr[n] = run;
}

__global__ __launch_bounds__(256) void scatter_kernel(const int* __restrict__ src,
        const int* __restrict__ dst, const float* __restrict__ ea,
        const int* __restrict__ rowptr, int* __restrict__ cursor,
        int* __restrict__ srcS, int* __restrict__ dstS, u16* __restrict__ eaS, int E) {
    int e = blockIdx.x * 256 + threadIdx.x;
    if (e >= E) return;
    int d = dst[e];
    int p = rowptr[d] + atomicAdd(&cursor[d], 1);
    srcS[p] = src[e];
    dstS[p] = d;
    const float* q = &ea[(size_t)e * EDIM];
    ushort4 v;
    v.x = f2bf(q[0]); v.y = f2bf(q[1]); v.z = f2bf(q[2]); v.w = f2bf(q[3]);
    *(ushort4*)&eaS[(size_t)p * 4] = v;
}

// embed + zero agg + graph counts (fused)
__global__ __launch_bounds__(HID) void embed_kernel(const int* __restrict__ z,
        const float* __restrict__ emb, u16* __restrict__ xb,
        float* __restrict__ agg, const int* __restrict__ batch,
        float* __restrict__ counts, int n) {
    int i = blockIdx.x;
    if (i >= n) return;
    int t = threadIdx.x;
    xb[(size_t)i * HID + t] = f2bf(emb[(size_t)z[i] * HID + t]);
    agg[(size_t)i * HID + t] = 0.f;
    if (t == 0) unsafeAtomicAdd(&counts[batch[i]], 1.0f);
}

// ---------------- edge MLP: 64 dst-sorted edges/block, 2x2 wave tiling ------
// R13: waves tile 2x2 (32 rows x 64 cols each) instead of 4-way N-split:
// halves A-fragment LDS reads (144->72 b128/block) and H reads (64->32),
// the two dominant LDS-pipe items. B-loads double but are L2-resident.
// LDS-staged A; A/H/M fully aliased -> 37.9 KB -> 4 blocks/CU.
__global__ __launch_bounds__(256) void edge_mfma(
        const u16* __restrict__ xin, const int* __restrict__ srcS,
        const int* __restrict__ dstS, const u16* __restrict__ eaS,
        const u16* __restrict__ w1f, const float* __restrict__ b1,
        const u16* __restrict__ w2f, const float* __restrict__ b2,
        float* __restrict__ agg, int nE) {
    // A: u16 [64][296] = 37888 B (dead after GEMM1)
    // H: u16 [64][136] = 17408 B (aliases A; dead after GEMM2)
    // M: f32 [64][132] = 33792 B (aliases A/H)
    __shared__ __align__(16) char smem[64 * 296 * 2];
    __shared__ int dsh[64];
    u16*   A = (u16*)smem;
    u16*   H = (u16*)smem;
    float* M = (float*)smem;

    const int t    = threadIdx.x;
    const int e0   = blockIdx.x * 64;
    const int wv   = t >> 6, lane = t & 63;
    const int wm   = wv >> 1;        // row half (0/1): rows wm*32 .. wm*32+31
    const int wn   = wv & 1;         // col half (0/1): cols wn*64 .. wn*64+63
    const int lrow = lane & 15;
    const int kq   = lane >> 4;
    const int kq8  = kq * 8;
    const int rq   = kq * 4;

    // ---- stage A: 64 rows x 32 chunks (16 src + 16 dst) of 8 bf16 ----
    #pragma unroll
    for (int it = 0; it < 8; ++it) {
        int slot = it * 256 + t;
        int row = slot >> 5, ch = slot & 31;
        int e = e0 + row; if (e >= nE) e = nE - 1;
        int node = (ch < 16) ? srcS[e] : dstS[e];
        us8 v = *(const us8*)&xin[(size_t)node * HID + (ch & 15) * 8];
        *(us8*)&A[row * 296 + ch * 8] = v;
    }
    if (t < 64) {
        int e = e0 + t;
        bool valid = e < nE; if (!valid) e = nE - 1;
        dsh[t] = valid ? dstS[e] : -1;
        ushort4 q = *(const ushort4*)&eaS[(size_t)e * 4];
        int base = t * 296 + 256;
        A[base + 0] = q.x; A[base + 1] = q.y; A[base + 2] = q.z; A[base + 3] = q.w;
        #pragma unroll
        for (int j = 4; j < 32; ++j) A[base + j] = 0;   // K-pad 260..287
    }
    __syncthreads();

    // ---- GEMM1: [64 x 288] @ [288 x 128]; wave: 2 m-tiles x 4 n-tiles ----
    f32x4 acc[2][4];
    #pragma unroll
    for (int j = 0; j < 4; ++j) {
        float b = b1[wn * 64 + j * 16 + lrow];
        #pragma unroll
        for (int mt = 0; mt < 2; ++mt)
            #pragma unroll
            for (int r = 0; r < 4; ++r) acc[mt][j][r] = b;
    }
    #pragma unroll
    for (int kt = 0; kt < 9; ++kt) {
        bf16x8 wf[4];
        #pragma unroll
        for (int j = 0; j < 4; ++j)
            wf[j] = *(const bf16x8*)&w1f[((size_t)(kt * 8 + wn * 4 + j) * 64 + lane) * 8];
        #pragma unroll
        for (int mt = 0; mt < 2; ++mt) {
            bf16x8 a = *(const bf16x8*)&A[((wm * 2 + mt) * 16 + lrow) * 296 + kt * 32 + kq8];
            #pragma unroll
            for (int j = 0; j < 4; ++j)
                acc[mt][j] = __builtin_amdgcn_mfma_f32_16x16x32_bf16(a, wf[j], acc[mt][j], 0, 0, 0);
        }
    }
    __syncthreads();   // all A reads done; region reused as H

    // silu -> H (C-layout -> A-layout)
    #pragma unroll
    for (int mt = 0; mt < 2; ++mt)
        #pragma unroll
        for (int j = 0; j < 4; ++j)
            #pragma unroll
            for (int r = 0; r < 4; ++r)
                H[((wm * 2 + mt) * 16 + rq + r) * 136 + wn * 64 + j * 16 + lrow] =
                    f2bf_fast(silu_f(acc[mt][j][r]));
    __syncthreads();

    // ---- GEMM2: [64 x 128] @ [128 x 128]; wave: 2 m-tiles x 4 n-tiles ----
    f32x4 acc2[2][4];
    #pragma unroll
    for (int j = 0; j < 4; ++j) {
        float b = b2[wn * 64 + j * 16 + lrow];
        #pragma unroll
        for (int mt = 0; mt < 2; ++mt)
            #pragma unroll
            for (int r = 0; r < 4; ++r) acc2[mt][j][r] = b;
    }
    #pragma unroll
    for (int kt = 0; kt < 4; ++kt) {
        bf16x8 wf[4];
        #pragma unroll
        for (int j = 0; j < 4; ++j)
            wf[j] = *(const bf16x8*)&w2f[((size_t)(kt * 8 + wn * 4 + j) * 64 + lane) * 8];
        #pragma unroll
        for (int mt = 0; mt < 2; ++mt) {
            bf16x8 a = *(const bf16x8*)&H[((wm * 2 + mt) * 16 + lrow) * 136 + kt * 32 + kq8];
            #pragma unroll
            for (int j = 0; j < 4; ++j)
                acc2[mt][j] = __builtin_amdgcn_mfma_f32_16x16x32_bf16(a, wf[j], acc2[mt][j], 0, 0, 0);
        }
    }
    __syncthreads();   // all H reads done; region reused as M

    // silu -> M (fp32 messages; stride 132 -> 2-way banked writes, free)
    #pragma unroll
    for (int mt = 0; mt < 2; ++mt)
        #pragma unroll
        for (int j = 0; j < 4; ++j)
            #pragma unroll
            for (int r = 0; r < 4; ++r)
                M[((wm * 2 + mt) * 16 + rq + r) * 132 + wn * 64 + j * 16 + lrow] =
                    silu_f(acc2[mt][j][r]);
    __syncthreads();

    // ---- segmented reduction over dst-sorted rows: one atomic per run ----
    {
        int col = t & 127;
        int r0  = (t >> 7) * 32;          // rows 0..31 or 32..63
        float run = 0.f;
        int   cur = dsh[r0];
        #pragma unroll 4
        for (int i = 0; i < 32; ++i) {
            int row = r0 + i;
            run += M[row * 132 + col];
            int nxt = (i == 31) ? -2 : dsh[row + 1];
            if (cur != nxt) {             // wave-uniform branch
                if (cur >= 0)
                    unsafeAtomicAdd(&agg[(size_t)cur * HID + col], run);
                run = 0.f; cur = nxt;
            }
        }
    }
}

// ---------------- node MLP: 32 nodes/block (2x grid for latency hiding) -----
// last==0: x = silu([x|agg]@nw+nb) in place, then zero own agg cells.
// last==1: scatter silu(...) directly into per-graph sums (no x store).
__global__ __launch_bounds__(256) void node_mfma(
        u16* __restrict__ xb, float* __restrict__ agg,
        const u16* __restrict__ nwf, const float* __restrict__ nb,
        const int* __restrict__ batch, float* __restrict__ sums,
        int last, int n) {
    const int t    = threadIdx.x;
    const int i0   = blockIdx.x * 32;
    const int wv   = t >> 6, lane = t & 63;
    const int lrow = lane & 15;
    const int kq   = lane >> 4;
    const int kq8  = kq * 8;
    const int rq   = kq * 4;

    int iN[2];
    #pragma unroll
    for (int mt = 0; mt < 2; ++mt) {
        int i = i0 + mt * 16 + lrow; if (i >= n) i = n - 1;
        iN[mt] = i;
    }

    f32x4 acc[2][2];
    {
        float bias0 = nb[wv * 32 + lrow], bias1 = nb[wv * 32 + 16 + lrow];
        #pragma unroll
        for (int mt = 0; mt < 2; ++mt)
            #pragma unroll
            for (int r = 0; r < 4; ++r) {
                acc[mt][0][r] = bias0; acc[mt][1][r] = bias1;
            }
    }
    #pragma unroll
    for (int kt = 0; kt < 4; ++kt) {     // x part (k 0..127)
        bf16x8 w0 = *(const bf16x8*)&nwf[((size_t)(kt * 8 + wv * 2 + 0) * 64 + lane) * 8];
        bf16x8 w1 = *(const bf16x8*)&nwf[((size_t)(kt * 8 + wv * 2 + 1) * 64 + lane) * 8];
        #pragma unroll
        for (int mt = 0; mt < 2; ++mt) {
            bf16x8 a = as_bf(*(const us8*)&xb[(size_t)iN[mt] * HID + kt * 32 + kq8]);
            acc[mt][0] = __builtin_amdgcn_mfma_f32_16x16x32_bf16(a, w0, acc[mt][0], 0, 0, 0);
            acc[mt][1] = __builtin_amdgcn_mfma_f32_16x16x32_bf16(a, w1, acc[mt][1], 0, 0, 0);
        }
    }
    #pragma unroll
    for (int kt = 4; kt < 8; ++kt) {     // agg part (k 128..255), fp32 -> bf16
        bf16x8 w0 = *(const bf16x8*)&nwf[((size_t)(kt * 8 + wv * 2 + 0) * 64 + lane) * 8];
        bf16x8 w1 = *(const bf16x8*)&nwf[((size_t)(kt * 8 + wv * 2 + 1) * 64 + lane) * 8];
        #pragma unroll
        for (int mt = 0; mt < 2; ++mt) {
            const float* p = &agg[(size_t)iN[mt] * HID + (kt - 4) * 32 + kq8];
            float4 f0 = *(const float4*)p;
            float4 f1 = *(const float4*)(p + 4);
            us8 av;
            av[0] = f2bf_fast(f0.x); av[1] = f2bf_fast(f0.y);
            av[2] = f2bf_fast(f0.z); av[3] = f2bf_fast(f0.w);
            av[4] = f2bf_fast(f1.x); av[5] = f2bf_fast(f1.y);
            av[6] = f2bf_fast(f1.z); av[7] = f2bf_fast(f1.w);
            bf16x8 a = as_bf(av);
            acc[mt][0] = __builtin_amdgcn_mfma_f32_16x16x32_bf16(a, w0, acc[mt][0], 0, 0, 0);
            acc[mt][1] = __builtin_amdgcn_mfma_f32_16x16x32_bf16(a, w1, acc[mt][1], 0, 0, 0);
        }
    }

    if (!last) {
        __syncthreads();   // all xb/agg reads in block complete before overwrite
        const float4 z4 = make_float4(0.f, 0.f, 0.f, 0.f);
        #pragma unroll
        for (int kt = 0; kt < 4; ++kt)
            #pragma unroll
            for (int mt = 0; mt < 2; ++mt) {
                float* p = &agg[(size_t)iN[mt] * HID + kt * 32 + kq8];
                *(float4*)p = z4; *(float4*)(p + 4) = z4;
            }
        #pragma unroll
        for (int mt = 0; mt < 2; ++mt)
            #pragma unroll
            for (int nt2 = 0; nt2 < 2; ++nt2)
                #pragma unroll
                for (int r = 0; r < 4; ++r) {
                    int i = i0 + mt * 16 + rq + r;
                    if (i < n)
                        xb[(size_t)i * HID + wv * 32 + nt2 * 16 + lrow] =
                            f2bf_fast(silu_f(acc[mt][nt2][r]));
                }
    } else {
        // final layer: scatter straight into per-graph sums
        #pragma unroll
        for (int mt = 0; mt < 2; ++mt)
            #pragma unroll
            for (int nt2 = 0; nt2 < 2; ++nt2)
                #pragma unroll
                for (int r = 0; r < 4; ++r) {
                    int i = i0 + mt * 16 + rq + r;
                    if (i < n) {
                        int b = batch[i];
                        unsafeAtomicAdd(&sums[(size_t)b * HID + wv * 32 + nt2 * 16 + lrow],
                                        silu_f(acc[mt][nt2][r]));
                    }
                }
    }
}

// ---------------- readout ---------------------------------------------------
__global__ __launch_bounds__(HID) void readout_kernel(
        const float* __restrict__ sums, const float* __restrict__ counts,
        const float* __restrict__ rw1, const float* __restrict__ rb1,
        const float* __restrict__ rw2, const float* __restrict__ rb2,
        float* __restrict__ pred) {
    __shared__ float gv[HID];
    __shared__ float hv[HID];
    const int g = blockIdx.x;
    const int t = threadIdx.x;
    float c = counts[g];
    if (c < 1.0f) c = 1.0f;
    gv[t] = sums[(size_t)g * HID + t] / c;   // cold path: keep exact division
    __syncthreads();
    float acc = rb1[t];
    for (int k4 = 0; k4 < 32; ++k4) {
        float4 mv = *(const float4*)&gv[k4 * 4];
        #pragma unroll
        for (int j = 0; j < 4; ++j)
            acc += ((const float*)&mv)[j] * rw1[(size_t)(k4 * 4 + j) * HID + t];
    }
    hv[t] = silu_f(acc) * rw2[t];
    __syncthreads();
    for (int s = HID / 2; s > 0; s >>= 1) {
        if (t < s) hv[t] += hv[t + s];
        __syncthreads();
    }
    if (t == 0) pred[g] = hv[0] + rb2[0];
}

extern "C" void kernel_launch(void* const* d_in, const int* in_sizes, int n_in,
                              void* d_out, int out_size, void* d_ws, size_t ws_size,
                              hipStream_t stream) {
    const int*   z          = (const int*)d_in[0];
    const int*   edge_index = (const int*)d_in[1];
    const float* edge_attr  = (const float*)d_in[2];
    const int*   batch      = (const int*)d_in[3];
    const float* emb        = (const float*)d_in[4];
    const float* ew1        = (const float*)d_in[5];
    const float* eb1        = (const float*)d_in[6];
    const float* ew2        = (const float*)d_in[7];
    const float* eb2        = (const float*)d_in[8];
    const float* nw         = (const float*)d_in[9];
    const float* nb         = (const float*)d_in[10];
    const float* rw1        = (const float*)d_in[11];
    const float* rb1        = (const float*)d_in[12];
    const float* rw2        = (const float*)d_in[13];
    const float* rb2        = (const float*)d_in[14];
    float* pred = (float*)d_out;

    const int N = in_sizes[0];
    const int E = in_sizes[1] / 2;
    const int G = out_size;
    const int* srcI = edge_index;
    const int* dstI = edge_index + E;

    char* base = (char*)d_ws;
    size_t off = 0;
    auto carve = [&](size_t bytes) -> char* {
        char* p = base + off;
        off = (off + bytes + 255) & ~(size_t)255;
        return p;
    };
    float* agg    = (float*)carve((size_t)N * HID * sizeof(float));
    float* sums   = (float*)carve((size_t)G * HID * sizeof(float));
    float* cnts_g = (float*)carve((size_t)G * sizeof(float));
    u16*   xb     = (u16*)carve((size_t)N * HID * sizeof(u16));
    int*   srcS   = (int*)carve((size_t)(E + 64) * sizeof(int));
    int*   dstS   = (int*)carve((size_t)(E + 64) * sizeof(int));
    u16*   eaS    = (u16*)carve((size_t)(E + 64) * 4 * sizeof(u16));
    int*   rowptr = (int*)carve((size_t)(N + 1) * sizeof(int));
    int*   cursor = (int*)carve((size_t)N * sizeof(int));
    int*   cnt    = (int*)carve((size_t)N * sizeof(int));
    u16*   w1f    = (u16*)carve((size_t)4 * 72 * 512 * sizeof(u16)); // KT=9
    u16*   w2f    = (u16*)carve((size_t)4 * 32 * 512 * sizeof(u16)); // KT=4
    u16*   nwf    = (u16*)carve((size_t)4 * 64 * 512 * sizeof(u16)); // KT=8

    // ---- fused setup: weight swizzle + zero cnt/cursor/sums/counts ----
    {
        long long total = (long long)T1 + T2 + T3 + 2LL * N + (long long)G * HID + G;
        int blocks = (int)((total + 255) / 256);
        setup_kernel<<<blocks, 256, 0, stream>>>(ew1, ew2, nw, w1f, w2f, nwf,
                                                 cnt, cursor, sums, cnts_g, N, G);
    }

    // ---- CSR build (dst-sorted edges) ----
    hist_kernel<<<(E + 255) / 256, 256, 0, stream>>>(dstI, cnt, E);
    scan_kernel<<<1, 1024, 0, stream>>>(cnt, rowptr, N);
    scatter_kernel<<<(E + 255) / 256, 256, 0, stream>>>(
        srcI, dstI, edge_attr, rowptr, cursor, srcS, dstS, eaS, E);

    // embed + zero agg + graph counts
    embed_kernel<<<N, HID, 0, stream>>>(z, emb, xb, agg, batch, cnts_g, N);

    for (int l = 0; l < 4; ++l) {
        edge_mfma<<<(E + 63) / 64, 256, 0, stream>>>(
            xb, srcS, dstS, eaS,
            w1f + (size_t)l * 72 * 512, eb1 + (size_t)l * HID,
            w2f + (size_t)l * 32 * 512, eb2 + (size_t)l * HID,
            agg, E);
        node_mfma<<<(N + 31) / 32, 256, 0, stream>>>(
            xb, agg, nwf + (size_t)l * 64 * 512, nb + (size_t)l * HID,
            batch, sums, (l == 3) ? 1 : 0, N);
    }

    readout_kernel<<<G, HID, 0, stream>>>(sums, cnts_g, rw1, rb1, rw2, rb2, pred);
}

// Round 14
// 1108.959 us; speedup vs baseline: 1.0310x; 1.0310x over previous
//
#include <hip/hip_runtime.h>
#include <math.h>

#define HID  128
#define EDIM 4

typedef unsigned short u16;
typedef u16    us8   __attribute__((ext_vector_type(8)));
typedef __bf16 bf16x8 __attribute__((ext_vector_type(8)));
typedef float  f32x4 __attribute__((ext_vector_type(4)));

// silu via hw rcp: v_rcp_f32 (~1 ulp) instead of IEEE div (10+ inst w/o fast-math)
__device__ __forceinline__ float silu_f(float v) {
    return v * __builtin_amdgcn_rcpf(1.0f + __expf(-v));
}
__device__ __forceinline__ u16 f2bf(float f) {   // RNE fp32->bf16 (cold paths)
    unsigned u = __float_as_uint(f);
    unsigned r = u + 0x7fffu + ((u >> 16) & 1u);
    return (u16)(r >> 16);
}
__device__ __forceinline__ u16 f2bf_fast(float f) {  // round-half-up, 2 ops (hot)
    return (u16)((__float_as_uint(f) + 0x8000u) >> 16);
}
__device__ __forceinline__ float bf2f(u16 s) {
    return __uint_as_float(((unsigned)s) << 16);
}
__device__ __forceinline__ bf16x8 as_bf(us8 v) {
    return __builtin_bit_cast(bf16x8, v);
}

// ---------------- fused setup: weight swizzle + zero-fills ------------------
__device__ __forceinline__ void wfrag_one(const float* __restrict__ w,
        u16* __restrict__ out, int KT, int K, int idx) {
    int lane = idx & 63;
    int f    = (idx >> 6) % (KT * 8);
    int l    = idx / (64 * KT * 8);
    int kt = f >> 3, nt = f & 7;
    int n  = nt * 16 + (lane & 15);
    int k0 = kt * 32 + ((lane >> 4) * 8);
    us8 v;
    #pragma unroll
    for (int j = 0; j < 8; ++j) {
        int k = k0 + j;
        v[j] = (k < K) ? f2bf(w[((size_t)l * K + k) * HID + n]) : (u16)0;
    }
    *(us8*)&out[((size_t)(l * KT * 8 + f) * 64 + lane) * 8] = v;
}

#define T1 (4 * 9 * 8 * 64)
#define T2 (4 * 4 * 8 * 64)
#define T3 (4 * 8 * 8 * 64)

__global__ __launch_bounds__(256) void setup_kernel(
        const float* __restrict__ ew1, const float* __restrict__ ew2,
        const float* __restrict__ nw,
        u16* __restrict__ w1f, u16* __restrict__ w2f, u16* __restrict__ nwf,
        int* __restrict__ cnt, int* __restrict__ cursor,
        float* __restrict__ sums, float* __restrict__ cnts_g, int N, int G) {
    int idx = blockIdx.x * 256 + threadIdx.x;
    if (idx < T1) { wfrag_one(ew1, w1f, 9, 2 * HID + EDIM, idx); return; }
    idx -= T1;
    if (idx < T2) { wfrag_one(ew2, w2f, 4, HID, idx); return; }
    idx -= T2;
    if (idx < T3) { wfrag_one(nw, nwf, 8, 2 * HID, idx); return; }
    idx -= T3;
    if (idx < N) { cnt[idx] = 0; return; }
    idx -= N;
    if (idx < N) { cursor[idx] = 0; return; }
    idx -= N;
    if (idx < G * HID) { sums[idx] = 0.f; return; }
    idx -= G * HID;
    if (idx < G) { cnts_g[idx] = 0.f; return; }
}

// ---------------- CSR build: hist -> scan -> scatter ------------------------
__global__ __launch_bounds__(256) void hist_kernel(const int* __restrict__ dst,
        int* __restrict__ cnt, int E) {
    int e = blockIdx.x * 256 + threadIdx.x;
    if (e < E) atomicAdd(&cnt[dst[e]], 1);
}

__global__ __launch_bounds__(1024) void scan_kernel(const int* __restrict__ cnt,
        int* __restrict__ rowptr, int n) {
    __shared__ int s[1024];
    const int t = threadIdx.x;
    const int chunk = (n + 1023) >> 10;
    int lo = t * chunk, hi = lo + chunk;
    if (lo > n) lo = n;
    if (hi > n) hi = n;
    int sum = 0;
    for (int i = lo; i < hi; ++i) sum += cnt[i];
    s[t] = sum;
    __syncthreads();
    for (int off = 1; off < 1024; off <<= 1) {
        int v = (t >= off) ? s[t - off] : 0;
        __syncthreads();
        s[t] += v;
        __syncthreads();
    }
    int run = s[t] - sum;
    for (int i = lo; i < hi; ++i) { rowptr[i] = run; run += cnt[i]; }
    if (t == 1023) rowptr[n] = run;
}

__global__ __launch_bounds__(256) void scatter_kernel(const int* __restrict__ src,
        const int* __restrict__ dst, const float* __restrict__ ea,
        const int* __restrict__ rowptr, int* __restrict__ cursor,
        int* __restrict__ srcS, int* __restrict__ dstS, u16* __restrict__ eaS, int E) {
    int e = blockIdx.x * 256 + threadIdx.x;
    if (e >= E) return;
    int d = dst[e];
    int p = rowptr[d] + atomicAdd(&cursor[d], 1);
    srcS[p] = src[e];
    dstS[p] = d;
    const float* q = &ea[(size_t)e * EDIM];
    ushort4 v;
    v.x = f2bf(q[0]); v.y = f2bf(q[1]); v.z = f2bf(q[2]); v.w = f2bf(q[3]);
    *(ushort4*)&eaS[(size_t)p * 4] = v;
}

// embed + zero agg + graph counts (fused)
__global__ __launch_bounds__(HID) void embed_kernel(const int* __restrict__ z,
        const float* __restrict__ emb, u16* __restrict__ xb,
        float* __restrict__ agg, const int* __restrict__ batch,
        float* __restrict__ counts, int n) {
    int i = blockIdx.x;
    if (i >= n) return;
    int t = threadIdx.x;
    xb[(size_t)i * HID + t] = f2bf(emb[(size_t)z[i] * HID + t]);
    agg[(size_t)i * HID + t] = 0.f;
    if (t == 0) unsafeAtomicAdd(&counts[batch[i]], 1.0f);
}

// ---------------- edge MLP: 64 dst-sorted edges/block, N-split waves --------
// R12-proven best (158 us): LDS-staged A; A/H/M fully aliased -> 37.9 KB ->
// 4 blocks/CU; segmented reduction over dst-sorted rows.
// FAILED variants (do not reintroduce): R9 XOR-swizzle 32KB (235 us),
// R13 2x2 wave tiling (164 us -- halved LDS conflicts but doubled B VMEM
// loads on the latency-critical path). Kernel is phase-chain latency-bound,
// not LDS-throughput-bound.
__global__ __launch_bounds__(256) void edge_mfma(
        const u16* __restrict__ xin, const int* __restrict__ srcS,
        const int* __restrict__ dstS, const u16* __restrict__ eaS,
        const u16* __restrict__ w1f, const float* __restrict__ b1,
        const u16* __restrict__ w2f, const float* __restrict__ b2,
        float* __restrict__ agg, int nE) {
    // A: u16 [64][296] = 37888 B (dead after GEMM1)
    // H: u16 [64][136] = 17408 B (aliases A; dead after GEMM2)
    // M: f32 [64][132] = 33792 B (aliases A/H)
    __shared__ __align__(16) char smem[64 * 296 * 2];
    __shared__ int dsh[64];
    u16*   A = (u16*)smem;
    u16*   H = (u16*)smem;
    float* M = (float*)smem;

    const int t    = threadIdx.x;
    const int e0   = blockIdx.x * 64;
    const int wv   = t >> 6, lane = t & 63;
    const int lrow = lane & 15;
    const int kq   = lane >> 4;
    const int kq8  = kq * 8;
    const int rq   = kq * 4;

    // ---- stage A: 64 rows x 32 chunks (16 src + 16 dst) of 8 bf16 ----
    #pragma unroll
    for (int it = 0; it < 8; ++it) {
        int slot = it * 256 + t;
        int row = slot >> 5, ch = slot & 31;
        int e = e0 + row; if (e >= nE) e = nE - 1;
        int node = (ch < 16) ? srcS[e] : dstS[e];
        us8 v = *(const us8*)&xin[(size_t)node * HID + (ch & 15) * 8];
        *(us8*)&A[row * 296 + ch * 8] = v;
    }
    if (t < 64) {
        int e = e0 + t;
        bool valid = e < nE; if (!valid) e = nE - 1;
        dsh[t] = valid ? dstS[e] : -1;
        ushort4 q = *(const ushort4*)&eaS[(size_t)e * 4];
        int base = t * 296 + 256;
        A[base + 0] = q.x; A[base + 1] = q.y; A[base + 2] = q.z; A[base + 3] = q.w;
        #pragma unroll
        for (int j = 4; j < 32; ++j) A[base + j] = 0;   // K-pad 260..287
    }
    __syncthreads();

    // ---- GEMM1: [64 x 288] @ [288 x 128], wave owns 32 cols, 4 m-tiles ----
    f32x4 acc[4][2];
    {
        float bias0 = b1[wv * 32 + lrow], bias1 = b1[wv * 32 + 16 + lrow];
        #pragma unroll
        for (int mt = 0; mt < 4; ++mt)
            #pragma unroll
            for (int r = 0; r < 4; ++r) {
                acc[mt][0][r] = bias0; acc[mt][1][r] = bias1;
            }
    }
    #pragma unroll
    for (int kt = 0; kt < 9; ++kt) {
        bf16x8 w0 = *(const bf16x8*)&w1f[((size_t)(kt * 8 + wv * 2 + 0) * 64 + lane) * 8];
        bf16x8 w1 = *(const bf16x8*)&w1f[((size_t)(kt * 8 + wv * 2 + 1) * 64 + lane) * 8];
        #pragma unroll
        for (int mt = 0; mt < 4; ++mt) {
            bf16x8 a = *(const bf16x8*)&A[(mt * 16 + lrow) * 296 + kt * 32 + kq8];
            acc[mt][0] = __builtin_amdgcn_mfma_f32_16x16x32_bf16(a, w0, acc[mt][0], 0, 0, 0);
            acc[mt][1] = __builtin_amdgcn_mfma_f32_16x16x32_bf16(a, w1, acc[mt][1], 0, 0, 0);
        }
    }
    __syncthreads();   // all A reads done; region reused as H

    // silu -> H (C-layout -> A-layout)
    #pragma unroll
    for (int mt = 0; mt < 4; ++mt)
        #pragma unroll
        for (int nt2 = 0; nt2 < 2; ++nt2)
            #pragma unroll
            for (int r = 0; r < 4; ++r)
                H[(mt * 16 + rq + r) * 136 + wv * 32 + nt2 * 16 + lrow] =
                    f2bf_fast(silu_f(acc[mt][nt2][r]));
    __syncthreads();

    // ---- GEMM2: [64 x 128] @ [128 x 128] ----
    f32x4 acc2[4][2];
    {
        float bias0 = b2[wv * 32 + lrow], bias1 = b2[wv * 32 + 16 + lrow];
        #pragma unroll
        for (int mt = 0; mt < 4; ++mt)
            #pragma unroll
            for (int r = 0; r < 4; ++r) {
                acc2[mt][0][r] = bias0; acc2[mt][1][r] = bias1;
            }
    }
    #pragma unroll
    for (int kt = 0; kt < 4; ++kt) {
        bf16x8 w0 = *(const bf16x8*)&w2f[((size_t)(kt * 8 + wv * 2 + 0) * 64 + lane) * 8];
        bf16x8 w1 = *(const bf16x8*)&w2f[((size_t)(kt * 8 + wv * 2 + 1) * 64 + lane) * 8];
        #pragma unroll
        for (int mt = 0; mt < 4; ++mt) {
            bf16x8 a = *(const bf16x8*)&H[(mt * 16 + lrow) * 136 + kt * 32 + kq8];
            acc2[mt][0] = __builtin_amdgcn_mfma_f32_16x16x32_bf16(a, w0, acc2[mt][0], 0, 0, 0);
            acc2[mt][1] = __builtin_amdgcn_mfma_f32_16x16x32_bf16(a, w1, acc2[mt][1], 0, 0, 0);
        }
    }
    __syncthreads();   // all H reads done; region reused as M

    // silu -> M (fp32 messages; stride 132 -> 2-way banked writes, free)
    #pragma unroll
    for (int mt = 0; mt < 4; ++mt)
        #pragma unroll
        for (int nt2 = 0; nt2 < 2; ++nt2)
            #pragma unroll
            for (int r = 0; r < 4; ++r)
                M[(mt * 16 + rq + r) * 132 + wv * 32 + nt2 * 16 + lrow] =
                    silu_f(acc2[mt][nt2][r]);
    __syncthreads();

    // ---- segmented reduction over dst-sorted rows: one atomic per run ----
    {
        int col = t & 127;
        int r0  = (t >> 7) * 32;          // rows 0..31 or 32..63
        float run = 0.f;
        int   cur = dsh[r0];
        #pragma unroll 4
        for (int i = 0; i < 32; ++i) {
            int row = r0 + i;
            run += M[row * 132 + col];
            int nxt = (i == 31) ? -2 : dsh[row + 1];
            if (cur != nxt) {             // wave-uniform branch
                if (cur >= 0)
                    unsafeAtomicAdd(&agg[(size_t)cur * HID + col], run);
                run = 0.f; cur = nxt;
            }
        }
    }
}

// ---------------- node MLP: 32 nodes/block (2x grid for latency hiding) -----
// last==0: x = silu([x|agg]@nw+nb) in place, then zero own agg cells.
// last==1: scatter silu(...) directly into per-graph sums (no x store).
__global__ __launch_bounds__(256) void node_mfma(
        u16* __restrict__ xb, float* __restrict__ agg,
        const u16* __restrict__ nwf, const float* __restrict__ nb,
        const int* __restrict__ batch, float* __restrict__ sums,
        int last, int n) {
    const int t    = threadIdx.x;
    const int i0   = blockIdx.x * 32;
    const int wv   = t >> 6, lane = t & 63;
    const int lrow = lane & 15;
    const int kq   = lane >> 4;
    const int kq8  = kq * 8;
    const int rq   = kq * 4;

    int iN[2];
    #pragma unroll
    for (int mt = 0; mt < 2; ++mt) {
        int i = i0 + mt * 16 + lrow; if (i >= n) i = n - 1;
        iN[mt] = i;
    }

    f32x4 acc[2][2];
    {
        float bias0 = nb[wv * 32 + lrow], bias1 = nb[wv * 32 + 16 + lrow];
        #pragma unroll
        for (int mt = 0; mt < 2; ++mt)
            #pragma unroll
            for (int r = 0; r < 4; ++r) {
                acc[mt][0][r] = bias0; acc[mt][1][r] = bias1;
            }
    }
    #pragma unroll
    for (int kt = 0; kt < 4; ++kt) {     // x part (k 0..127)
        bf16x8 w0 = *(const bf16x8*)&nwf[((size_t)(kt * 8 + wv * 2 + 0) * 64 + lane) * 8];
        bf16x8 w1 = *(const bf16x8*)&nwf[((size_t)(kt * 8 + wv * 2 + 1) * 64 + lane) * 8];
        #pragma unroll
        for (int mt = 0; mt < 2; ++mt) {
            bf16x8 a = as_bf(*(const us8*)&xb[(size_t)iN[mt] * HID + kt * 32 + kq8]);
            acc[mt][0] = __builtin_amdgcn_mfma_f32_16x16x32_bf16(a, w0, acc[mt][0], 0, 0, 0);
            acc[mt][1] = __builtin_amdgcn_mfma_f32_16x16x32_bf16(a, w1, acc[mt][1], 0, 0, 0);
        }
    }
    #pragma unroll
    for (int kt = 4; kt < 8; ++kt) {     // agg part (k 128..255), fp32 -> bf16
        bf16x8 w0 = *(const bf16x8*)&nwf[((size_t)(kt * 8 + wv * 2 + 0) * 64 + lane) * 8];
        bf16x8 w1 = *(const bf16x8*)&nwf[((size_t)(kt * 8 + wv * 2 + 1) * 64 + lane) * 8];
        #pragma unroll
        for (int mt = 0; mt < 2; ++mt) {
            const float* p = &agg[(size_t)iN[mt] * HID + (kt - 4) * 32 + kq8];
            float4 f0 = *(const float4*)p;
            float4 f1 = *(const float4*)(p + 4);
            us8 av;
            av[0] = f2bf_fast(f0.x); av[1] = f2bf_fast(f0.y);
            av[2] = f2bf_fast(f0.z); av[3] = f2bf_fast(f0.w);
            av[4] = f2bf_fast(f1.x); av[5] = f2bf_fast(f1.y);
            av[6] = f2bf_fast(f1.z); av[7] = f2bf_fast(f1.w);
            bf16x8 a = as_bf(av);
            acc[mt][0] = __builtin_amdgcn_mfma_f32_16x16x32_bf16(a, w0, acc[mt][0], 0, 0, 0);
            acc[mt][1] = __builtin_amdgcn_mfma_f32_16x16x32_bf16(a, w1, acc[mt][1], 0, 0, 0);
        }
    }

    if (!last) {
        __syncthreads();   // all xb/agg reads in block complete before overwrite
        const float4 z4 = make_float4(0.f, 0.f, 0.f, 0.f);
        #pragma unroll
        for (int kt = 0; kt < 4; ++kt)
            #pragma unroll
            for (int mt = 0; mt < 2; ++mt) {
                float* p = &agg[(size_t)iN[mt] * HID + kt * 32 + kq8];
                *(float4*)p = z4; *(float4*)(p + 4) = z4;
            }
        #pragma unroll
        for (int mt = 0; mt < 2; ++mt)
            #pragma unroll
            for (int nt2 = 0; nt2 < 2; ++nt2)
                #pragma unroll
                for (int r = 0; r < 4; ++r) {
                    int i = i0 + mt * 16 + rq + r;
                    if (i < n)
                        xb[(size_t)i * HID + wv * 32 + nt2 * 16 + lrow] =
                            f2bf_fast(silu_f(acc[mt][nt2][r]));
                }
    } else {
        // final layer: scatter straight into per-graph sums
        #pragma unroll
        for (int mt = 0; mt < 2; ++mt)
            #pragma unroll
            for (int nt2 = 0; nt2 < 2; ++nt2)
                #pragma unroll
                for (int r = 0; r < 4; ++r) {
                    int i = i0 + mt * 16 + rq + r;
                    if (i < n) {
                        int b = batch[i];
                        unsafeAtomicAdd(&sums[(size_t)b * HID + wv * 32 + nt2 * 16 + lrow],
                                        silu_f(acc[mt][nt2][r]));
                    }
                }
    }
}

// ---------------- readout ---------------------------------------------------
__global__ __launch_bounds__(HID) void readout_kernel(
        const float* __restrict__ sums, const float* __restrict__ counts,
        const float* __restrict__ rw1, const float* __restrict__ rb1,
        const float* __restrict__ rw2, const float* __restrict__ rb2,
        float* __restrict__ pred) {
    __shared__ float gv[HID];
    __shared__ float hv[HID];
    const int g = blockIdx.x;
    const int t = threadIdx.x;
    float c = counts[g];
    if (c < 1.0f) c = 1.0f;
    gv[t] = sums[(size_t)g * HID + t] / c;   // cold path: keep exact division
    __syncthreads();
    float acc = rb1[t];
    for (int k4 = 0; k4 < 32; ++k4) {
        float4 mv = *(const float4*)&gv[k4 * 4];
        #pragma unroll
        for (int j = 0; j < 4; ++j)
            acc += ((const float*)&mv)[j] * rw1[(size_t)(k4 * 4 + j) * HID + t];
    }
    hv[t] = silu_f(acc) * rw2[t];
    __syncthreads();
    for (int s = HID / 2; s > 0; s >>= 1) {
        if (t < s) hv[t] += hv[t + s];
        __syncthreads();
    }
    if (t == 0) pred[g] = hv[0] + rb2[0];
}

extern "C" void kernel_launch(void* const* d_in, const int* in_sizes, int n_in,
                              void* d_out, int out_size, void* d_ws, size_t ws_size,
                              hipStream_t stream) {
    const int*   z          = (const int*)d_in[0];
    const int*   edge_index = (const int*)d_in[1];
    const float* edge_attr  = (const float*)d_in[2];
    const int*   batch      = (const int*)d_in[3];
    const float* emb        = (const float*)d_in[4];
    const float* ew1        = (const float*)d_in[5];
    const float* eb1        = (const float*)d_in[6];
    const float* ew2        = (const float*)d_in[7];
    const float* eb2        = (const float*)d_in[8];
    const float* nw         = (const float*)d_in[9];
    const float* nb         = (const float*)d_in[10];
    const float* rw1        = (const float*)d_in[11];
    const float* rb1        = (const float*)d_in[12];
    const float* rw2        = (const float*)d_in[13];
    const float* rb2        = (const float*)d_in[14];
    float* pred = (float*)d_out;

    const int N = in_sizes[0];
    const int E = in_sizes[1] / 2;
    const int G = out_size;
    const int* srcI = edge_index;
    const int* dstI = edge_index + E;

    char* base = (char*)d_ws;
    size_t off = 0;
    auto carve = [&](size_t bytes) -> char* {
        char* p = base + off;
        off = (off + bytes + 255) & ~(size_t)255;
        return p;
    };
    float* agg    = (float*)carve((size_t)N * HID * sizeof(float));
    float* sums   = (float*)carve((size_t)G * HID * sizeof(float));
    float* cnts_g = (float*)carve((size_t)G * sizeof(float));
    u16*   xb     = (u16*)carve((size_t)N * HID * sizeof(u16));
    int*   srcS   = (int*)carve((size_t)(E + 64) * sizeof(int));
    int*   dstS   = (int*)carve((size_t)(E + 64) * sizeof(int));
    u16*   eaS    = (u16*)carve((size_t)(E + 64) * 4 * sizeof(u16));
    int*   rowptr = (int*)carve((size_t)(N + 1) * sizeof(int));
    int*   cursor = (int*)carve((size_t)N * sizeof(int));
    int*   cnt    = (int*)carve((size_t)N * sizeof(int));
    u16*   w1f    = (u16*)carve((size_t)4 * 72 * 512 * sizeof(u16)); // KT=9
    u16*   w2f    = (u16*)carve((size_t)4 * 32 * 512 * sizeof(u16)); // KT=4
    u16*   nwf    = (u16*)carve((size_t)4 * 64 * 512 * sizeof(u16)); // KT=8

    // ---- fused setup: weight swizzle + zero cnt/cursor/sums/counts ----
    {
        long long total = (long long)T1 + T2 + T3 + 2LL * N + (long long)G * HID + G;
        int blocks = (int)((total + 255) / 256);
        setup_kernel<<<blocks, 256, 0, stream>>>(ew1, ew2, nw, w1f, w2f, nwf,
                                                 cnt, cursor, sums, cnts_g, N, G);
    }

    // ---- CSR build (dst-sorted edges) ----
    hist_kernel<<<(E + 255) / 256, 256, 0, stream>>>(dstI, cnt, E);
    scan_kernel<<<1, 1024, 0, stream>>>(cnt, rowptr, N);
    scatter_kernel<<<(E + 255) / 256, 256, 0, stream>>>(
        srcI, dstI, edge_attr, rowptr, cursor, srcS, dstS, eaS, E);

    // embed + zero agg + graph counts
    embed_kernel<<<N, HID, 0, stream>>>(z, emb, xb, agg, batch, cnts_g, N);

    for (int l = 0; l < 4; ++l) {
        edge_mfma<<<(E + 63) / 64, 256, 0, stream>>>(
            xb, srcS, dstS, eaS,
            w1f + (size_t)l * 72 * 512, eb1 + (size_t)l * HID,
            w2f + (size_t)l * 32 * 512, eb2 + (size_t)l * HID,
            agg, E);
        node_mfma<<<(N + 31) / 32, 256, 0, stream>>>(
            xb, agg, nwf + (size_t)l * 64 * 512, nb + (size_t)l * HID,
            batch, sums, (l == 3) ? 1 : 0, N);
    }

    readout_kernel<<<G, HID, 0, stream>>>(sums, cnts_g, rw1, rb1, rw2, rb2, pred);
}

// Round 15
// 1104.683 us; speedup vs baseline: 1.0350x; 1.0039x over previous
//
#include <hip/hip_runtime.h>
#include <math.h>

#define HID  128
#define EDIM 4

typedef unsigned short u16;
typedef u16    us8   __attribute__((ext_vector_type(8)));
typedef __bf16 bf16x8 __attribute__((ext_vector_type(8)));
typedef float  f32x4 __attribute__((ext_vector_type(4)));

// silu via hw rcp: v_rcp_f32 (~1 ulp) instead of IEEE div (10+ inst w/o fast-math)
__device__ __forceinline__ float silu_f(float v) {
    return v * __builtin_amdgcn_rcpf(1.0f + __expf(-v));
}
__device__ __forceinline__ u16 f2bf(float f) {   // RNE fp32->bf16 (cold paths)
    unsigned u = __float_as_uint(f);
    unsigned r = u + 0x7fffu + ((u >> 16) & 1u);
    return (u16)(r >> 16);
}
__device__ __forceinline__ u16 f2bf_fast(float f) {  // round-half-up, 2 ops (hot)
    return (u16)((__float_as_uint(f) + 0x8000u) >> 16);
}
__device__ __forceinline__ float bf2f(u16 s) {
    return __uint_as_float(((unsigned)s) << 16);
}
__device__ __forceinline__ bf16x8 as_bf(us8 v) {
    return __builtin_bit_cast(bf16x8, v);
}

// ---------------- fused setup: weight swizzle + zero-fills ------------------
__device__ __forceinline__ void wfrag_one(const float* __restrict__ w,
        u16* __restrict__ out, int KT, int K, int idx) {
    int lane = idx & 63;
    int f    = (idx >> 6) % (KT * 8);
    int l    = idx / (64 * KT * 8);
    int kt = f >> 3, nt = f & 7;
    int n  = nt * 16 + (lane & 15);
    int k0 = kt * 32 + ((lane >> 4) * 8);
    us8 v;
    #pragma unroll
    for (int j = 0; j < 8; ++j) {
        int k = k0 + j;
        v[j] = (k < K) ? f2bf(w[((size_t)l * K + k) * HID + n]) : (u16)0;
    }
    *(us8*)&out[((size_t)(l * KT * 8 + f) * 64 + lane) * 8] = v;
}

#define T1 (4 * 9 * 8 * 64)
#define T2 (4 * 4 * 8 * 64)
#define T3 (4 * 8 * 8 * 64)

__global__ __launch_bounds__(256) void setup_kernel(
        const float* __restrict__ ew1, const float* __restrict__ ew2,
        const float* __restrict__ nw,
        u16* __restrict__ w1f, u16* __restrict__ w2f, u16* __restrict__ nwf,
        int* __restrict__ cnt, int* __restrict__ cursor,
        float* __restrict__ sums, float* __restrict__ cnts_g, int N, int G) {
    int idx = blockIdx.x * 256 + threadIdx.x;
    if (idx < T1) { wfrag_one(ew1, w1f, 9, 2 * HID + EDIM, idx); return; }
    idx -= T1;
    if (idx < T2) { wfrag_one(ew2, w2f, 4, HID, idx); return; }
    idx -= T2;
    if (idx < T3) { wfrag_one(nw, nwf, 8, 2 * HID, idx); return; }
    idx -= T3;
    if (idx < N) { cnt[idx] = 0; return; }
    idx -= N;
    if (idx < N) { cursor[idx] = 0; return; }
    idx -= N;
    if (idx < G * HID) { sums[idx] = 0.f; return; }
    idx -= G * HID;
    if (idx < G) { cnts_g[idx] = 0.f; return; }
}

// ---------------- CSR build: hist -> scan -> scatter ------------------------
__global__ __launch_bounds__(256) void hist_kernel(const int* __restrict__ dst,
        int* __restrict__ cnt, int E) {
    int e = blockIdx.x * 256 + threadIdx.x;
    if (e < E) atomicAdd(&cnt[dst[e]], 1);
}

__global__ __launch_bounds__(1024) void scan_kernel(const int* __restrict__ cnt,
        int* __restrict__ rowptr, int n) {
    __shared__ int s[1024];
    const int t = threadIdx.x;
    const int chunk = (n + 1023) >> 10;
    int lo = t * chunk, hi = lo + chunk;
    if (lo > n) lo = n;
    if (hi > n) hi = n;
    int sum = 0;
    for (int i = lo; i < hi; ++i) sum += cnt[i];
    s[t] = sum;
    __syncthreads();
    for (int off = 1; off < 1024; off <<= 1) {
        int v = (t >= off) ? s[t - off] : 0;
        __syncthreads();
        s[t] += v;
        __syncthreads();
    }
    int run = s[t] - sum;
    for (int i = lo; i < hi; ++i) { rowptr[i] = run; run += cnt[i]; }
    if (t == 1023) rowptr[n] = run;
}

__global__ __launch_bounds__(256) void scatter_kernel(const int* __restrict__ src,
        const int* __restrict__ dst, const float* __restrict__ ea,
        const int* __restrict__ rowptr, int* __restrict__ cursor,
        int* __restrict__ srcS, int* __restrict__ dstS, u16* __restrict__ eaS, int E) {
    int e = blockIdx.x * 256 + threadIdx.x;
    if (e >= E) return;
    int d = dst[e];
    int p = rowptr[d] + atomicAdd(&cursor[d], 1);
    srcS[p] = src[e];
    dstS[p] = d;
    const float* q = &ea[(size_t)e * EDIM];
    ushort4 v;
    v.x = f2bf(q[0]); v.y = f2bf(q[1]); v.z = f2bf(q[2]); v.w = f2bf(q[3]);
    *(ushort4*)&eaS[(size_t)p * 4] = v;
}

// embed + zero agg + graph counts (fused)
__global__ __launch_bounds__(HID) void embed_kernel(const int* __restrict__ z,
        const float* __restrict__ emb, u16* __restrict__ xb,
        float* __restrict__ agg, const int* __restrict__ batch,
        float* __restrict__ counts, int n) {
    int i = blockIdx.x;
    if (i >= n) return;
    int t = threadIdx.x;
    xb[(size_t)i * HID + t] = f2bf(emb[(size_t)z[i] * HID + t]);
    agg[(size_t)i * HID + t] = 0.f;
    if (t == 0) unsafeAtomicAdd(&counts[batch[i]], 1.0f);
}

// ---------------- edge MLP: 64 dst-sorted edges/block, N-split waves --------
// R12-proven core + R15: wave-local segmented scan (each wave reduces only
// the 32 M-columns it wrote) -> final __syncthreads removed (4 barriers).
// FAILED variants (do not reintroduce): R9 XOR-swizzle 32KB (235 us),
// R13 2x2 wave tiling (164 us). Kernel is phase-chain latency-bound.
__global__ __launch_bounds__(256) void edge_mfma(
        const u16* __restrict__ xin, const int* __restrict__ srcS,
        const int* __restrict__ dstS, const u16* __restrict__ eaS,
        const u16* __restrict__ w1f, const float* __restrict__ b1,
        const u16* __restrict__ w2f, const float* __restrict__ b2,
        float* __restrict__ agg, int nE) {
    // A: u16 [64][296] = 37888 B (dead after GEMM1)
    // H: u16 [64][136] = 17408 B (aliases A; dead after GEMM2)
    // M: f32 [64][132] = 33792 B (aliases A/H)
    __shared__ __align__(16) char smem[64 * 296 * 2];
    __shared__ int dsh[64];
    u16*   A = (u16*)smem;
    u16*   H = (u16*)smem;
    float* M = (float*)smem;

    const int t    = threadIdx.x;
    const int e0   = blockIdx.x * 64;
    const int wv   = t >> 6, lane = t & 63;
    const int lrow = lane & 15;
    const int kq   = lane >> 4;
    const int kq8  = kq * 8;
    const int rq   = kq * 4;

    // ---- stage A: 64 rows x 32 chunks (16 src + 16 dst) of 8 bf16 ----
    #pragma unroll
    for (int it = 0; it < 8; ++it) {
        int slot = it * 256 + t;
        int row = slot >> 5, ch = slot & 31;
        int e = e0 + row; if (e >= nE) e = nE - 1;
        int node = (ch < 16) ? srcS[e] : dstS[e];
        us8 v = *(const us8*)&xin[(size_t)node * HID + (ch & 15) * 8];
        *(us8*)&A[row * 296 + ch * 8] = v;
    }
    if (t < 64) {
        int e = e0 + t;
        bool valid = e < nE; if (!valid) e = nE - 1;
        dsh[t] = valid ? dstS[e] : -1;
        ushort4 q = *(const ushort4*)&eaS[(size_t)e * 4];
        int base = t * 296 + 256;
        A[base + 0] = q.x; A[base + 1] = q.y; A[base + 2] = q.z; A[base + 3] = q.w;
        #pragma unroll
        for (int j = 4; j < 32; ++j) A[base + j] = 0;   // K-pad 260..287
    }
    __syncthreads();

    // ---- GEMM1: [64 x 288] @ [288 x 128], wave owns 32 cols, 4 m-tiles ----
    f32x4 acc[4][2];
    {
        float bias0 = b1[wv * 32 + lrow], bias1 = b1[wv * 32 + 16 + lrow];
        #pragma unroll
        for (int mt = 0; mt < 4; ++mt)
            #pragma unroll
            for (int r = 0; r < 4; ++r) {
                acc[mt][0][r] = bias0; acc[mt][1][r] = bias1;
            }
    }
    #pragma unroll
    for (int kt = 0; kt < 9; ++kt) {
        bf16x8 w0 = *(const bf16x8*)&w1f[((size_t)(kt * 8 + wv * 2 + 0) * 64 + lane) * 8];
        bf16x8 w1 = *(const bf16x8*)&w1f[((size_t)(kt * 8 + wv * 2 + 1) * 64 + lane) * 8];
        #pragma unroll
        for (int mt = 0; mt < 4; ++mt) {
            bf16x8 a = *(const bf16x8*)&A[(mt * 16 + lrow) * 296 + kt * 32 + kq8];
            acc[mt][0] = __builtin_amdgcn_mfma_f32_16x16x32_bf16(a, w0, acc[mt][0], 0, 0, 0);
            acc[mt][1] = __builtin_amdgcn_mfma_f32_16x16x32_bf16(a, w1, acc[mt][1], 0, 0, 0);
        }
    }
    __syncthreads();   // all A reads done; region reused as H

    // silu -> H (C-layout -> A-layout)
    #pragma unroll
    for (int mt = 0; mt < 4; ++mt)
        #pragma unroll
        for (int nt2 = 0; nt2 < 2; ++nt2)
            #pragma unroll
            for (int r = 0; r < 4; ++r)
                H[(mt * 16 + rq + r) * 136 + wv * 32 + nt2 * 16 + lrow] =
                    f2bf_fast(silu_f(acc[mt][nt2][r]));
    __syncthreads();

    // ---- GEMM2: [64 x 128] @ [128 x 128] ----
    f32x4 acc2[4][2];
    {
        float bias0 = b2[wv * 32 + lrow], bias1 = b2[wv * 32 + 16 + lrow];
        #pragma unroll
        for (int mt = 0; mt < 4; ++mt)
            #pragma unroll
            for (int r = 0; r < 4; ++r) {
                acc2[mt][0][r] = bias0; acc2[mt][1][r] = bias1;
            }
    }
    #pragma unroll
    for (int kt = 0; kt < 4; ++kt) {
        bf16x8 w0 = *(const bf16x8*)&w2f[((size_t)(kt * 8 + wv * 2 + 0) * 64 + lane) * 8];
        bf16x8 w1 = *(const bf16x8*)&w2f[((size_t)(kt * 8 + wv * 2 + 1) * 64 + lane) * 8];
        #pragma unroll
        for (int mt = 0; mt < 4; ++mt) {
            bf16x8 a = *(const bf16x8*)&H[(mt * 16 + lrow) * 136 + kt * 32 + kq8];
            acc2[mt][0] = __builtin_amdgcn_mfma_f32_16x16x32_bf16(a, w0, acc2[mt][0], 0, 0, 0);
            acc2[mt][1] = __builtin_amdgcn_mfma_f32_16x16x32_bf16(a, w1, acc2[mt][1], 0, 0, 0);
        }
    }
    __syncthreads();   // all H reads complete before M overwrites (aliased WAR)

    // silu -> M (fp32 messages; stride 132 -> 2-way banked writes, free)
    #pragma unroll
    for (int mt = 0; mt < 4; ++mt)
        #pragma unroll
        for (int nt2 = 0; nt2 < 2; ++nt2)
            #pragma unroll
            for (int r = 0; r < 4; ++r)
                M[(mt * 16 + rq + r) * 132 + wv * 32 + nt2 * 16 + lrow] =
                    silu_f(acc2[mt][nt2][r]);

    // ---- wave-local segmented reduction (NO barrier: wave wv scans exactly
    // the 32 cols it wrote; intra-wave DS program order + compiler lgkmcnt
    // waits guarantee visibility). Same (col,half) partition as before ->
    // bit-identical summation order.
    {
        int col = wv * 32 + (lane & 31);
        int r0  = (lane >> 5) * 32;       // rows 0..31 or 32..63
        float run = 0.f;
        int   cur = dsh[r0];
        #pragma unroll 4
        for (int i = 0; i < 32; ++i) {
            int row = r0 + i;
            run += M[row * 132 + col];
            int nxt = (i == 31) ? -2 : dsh[row + 1];
            if (cur != nxt) {             // wave-uniform branch
                if (cur >= 0)
                    unsafeAtomicAdd(&agg[(size_t)cur * HID + col], run);
                run = 0.f; cur = nxt;
            }
        }
    }
}

// ---------------- node MLP: 32 nodes/block (2x grid for latency hiding) -----
// last==0: x = silu([x|agg]@nw+nb) in place, then zero own agg cells.
// last==1: scatter silu(...) directly into per-graph sums (no x store).
__global__ __launch_bounds__(256) void node_mfma(
        u16* __restrict__ xb, float* __restrict__ agg,
        const u16* __restrict__ nwf, const float* __restrict__ nb,
        const int* __restrict__ batch, float* __restrict__ sums,
        int last, int n) {
    const int t    = threadIdx.x;
    const int i0   = blockIdx.x * 32;
    const int wv   = t >> 6, lane = t & 63;
    const int lrow = lane & 15;
    const int kq   = lane >> 4;
    const int kq8  = kq * 8;
    const int rq   = kq * 4;

    int iN[2];
    #pragma unroll
    for (int mt = 0; mt < 2; ++mt) {
        int i = i0 + mt * 16 + lrow; if (i >= n) i = n - 1;
        iN[mt] = i;
    }

    f32x4 acc[2][2];
    {
        float bias0 = nb[wv * 32 + lrow], bias1 = nb[wv * 32 + 16 + lrow];
        #pragma unroll
        for (int mt = 0; mt < 2; ++mt)
            #pragma unroll
            for (int r = 0; r < 4; ++r) {
                acc[mt][0][r] = bias0; acc[mt][1][r] = bias1;
            }
    }
    #pragma unroll
    for (int kt = 0; kt < 4; ++kt) {     // x part (k 0..127)
        bf16x8 w0 = *(const bf16x8*)&nwf[((size_t)(kt * 8 + wv * 2 + 0) * 64 + lane) * 8];
        bf16x8 w1 = *(const bf16x8*)&nwf[((size_t)(kt * 8 + wv * 2 + 1) * 64 + lane) * 8];
        #pragma unroll
        for (int mt = 0; mt < 2; ++mt) {
            bf16x8 a = as_bf(*(const us8*)&xb[(size_t)iN[mt] * HID + kt * 32 + kq8]);
            acc[mt][0] = __builtin_amdgcn_mfma_f32_16x16x32_bf16(a, w0, acc[mt][0], 0, 0, 0);
            acc[mt][1] = __builtin_amdgcn_mfma_f32_16x16x32_bf16(a, w1, acc[mt][1], 0, 0, 0);
        }
    }
    #pragma unroll
    for (int kt = 4; kt < 8; ++kt) {     // agg part (k 128..255), fp32 -> bf16
        bf16x8 w0 = *(const bf16x8*)&nwf[((size_t)(kt * 8 + wv * 2 + 0) * 64 + lane) * 8];
        bf16x8 w1 = *(const bf16x8*)&nwf[((size_t)(kt * 8 + wv * 2 + 1) * 64 + lane) * 8];
        #pragma unroll
        for (int mt = 0; mt < 2; ++mt) {
            const float* p = &agg[(size_t)iN[mt] * HID + (kt - 4) * 32 + kq8];
            float4 f0 = *(const float4*)p;
            float4 f1 = *(const float4*)(p + 4);
            us8 av;
            av[0] = f2bf_fast(f0.x); av[1] = f2bf_fast(f0.y);
            av[2] = f2bf_fast(f0.z); av[3] = f2bf_fast(f0.w);
            av[4] = f2bf_fast(f1.x); av[5] = f2bf_fast(f1.y);
            av[6] = f2bf_fast(f1.z); av[7] = f2bf_fast(f1.w);
            bf16x8 a = as_bf(av);
            acc[mt][0] = __builtin_amdgcn_mfma_f32_16x16x32_bf16(a, w0, acc[mt][0], 0, 0, 0);
            acc[mt][1] = __builtin_amdgcn_mfma_f32_16x16x32_bf16(a, w1, acc[mt][1], 0, 0, 0);
        }
    }

    if (!last) {
        __syncthreads();   // all xb/agg reads in block complete before overwrite
        const float4 z4 = make_float4(0.f, 0.f, 0.f, 0.f);
        #pragma unroll
        for (int kt = 0; kt < 4; ++kt)
            #pragma unroll
            for (int mt = 0; mt < 2; ++mt) {
                float* p = &agg[(size_t)iN[mt] * HID + kt * 32 + kq8];
                *(float4*)p = z4; *(float4*)(p + 4) = z4;
            }
        #pragma unroll
        for (int mt = 0; mt < 2; ++mt)
            #pragma unroll
            for (int nt2 = 0; nt2 < 2; ++nt2)
                #pragma unroll
                for (int r = 0; r < 4; ++r) {
                    int i = i0 + mt * 16 + rq + r;
                    if (i < n)
                        xb[(size_t)i * HID + wv * 32 + nt2 * 16 + lrow] =
                            f2bf_fast(silu_f(acc[mt][nt2][r]));
                }
    } else {
        // final layer: scatter straight into per-graph sums
        #pragma unroll
        for (int mt = 0; mt < 2; ++mt)
            #pragma unroll
            for (int nt2 = 0; nt2 < 2; ++nt2)
                #pragma unroll
                for (int r = 0; r < 4; ++r) {
                    int i = i0 + mt * 16 + rq + r;
                    if (i < n) {
                        int b = batch[i];
                        unsafeAtomicAdd(&sums[(size_t)b * HID + wv * 32 + nt2 * 16 + lrow],
                                        silu_f(acc[mt][nt2][r]));
                    }
                }
    }
}

// ---------------- readout ---------------------------------------------------
__global__ __launch_bounds__(HID) void readout_kernel(
        const float* __restrict__ sums, const float* __restrict__ counts,
        const float* __restrict__ rw1, const float* __restrict__ rb1,
        const float* __restrict__ rw2, const float* __restrict__ rb2,
        float* __restrict__ pred) {
    __shared__ float gv[HID];
    __shared__ float hv[HID];
    const int g = blockIdx.x;
    const int t = threadIdx.x;
    float c = counts[g];
    if (c < 1.0f) c = 1.0f;
    gv[t] = sums[(size_t)g * HID + t] / c;   // cold path: keep exact division
    __syncthreads();
    float acc = rb1[t];
    for (int k4 = 0; k4 < 32; ++k4) {
        float4 mv = *(const float4*)&gv[k4 * 4];
        #pragma unroll
        for (int j = 0; j < 4; ++j)
            acc += ((const float*)&mv)[j] * rw1[(size_t)(k4 * 4 + j) * HID + t];
    }
    hv[t] = silu_f(acc) * rw2[t];
    __syncthreads();
    for (int s = HID / 2; s > 0; s >>= 1) {
        if (t < s) hv[t] += hv[t + s];
        __syncthreads();
    }
    if (t == 0) pred[g] = hv[0] + rb2[0];
}

extern "C" void kernel_launch(void* const* d_in, const int* in_sizes, int n_in,
                              void* d_out, int out_size, void* d_ws, size_t ws_size,
                              hipStream_t stream) {
    const int*   z          = (const int*)d_in[0];
    const int*   edge_index = (const int*)d_in[1];
    const float* edge_attr  = (const float*)d_in[2];
    const int*   batch      = (const int*)d_in[3];
    const float* emb        = (const float*)d_in[4];
    const float* ew1        = (const float*)d_in[5];
    const float* eb1        = (const float*)d_in[6];
    const float* ew2        = (const float*)d_in[7];
    const float* eb2        = (const float*)d_in[8];
    const float* nw         = (const float*)d_in[9];
    const float* nb         = (const float*)d_in[10];
    const float* rw1        = (const float*)d_in[11];
    const float* rb1        = (const float*)d_in[12];
    const float* rw2        = (const float*)d_in[13];
    const float* rb2        = (const float*)d_in[14];
    float* pred = (float*)d_out;

    const int N = in_sizes[0];
    const int E = in_sizes[1] / 2;
    const int G = out_size;
    const int* srcI = edge_index;
    const int* dstI = edge_index + E;

    char* base = (char*)d_ws;
    size_t off = 0;
    auto carve = [&](size_t bytes) -> char* {
        char* p = base + off;
        off = (off + bytes + 255) & ~(size_t)255;
        return p;
    };
    float* agg    = (float*)carve((size_t)N * HID * sizeof(float));
    float* sums   = (float*)carve((size_t)G * HID * sizeof(float));
    float* cnts_g = (float*)carve((size_t)G * sizeof(float));
    u16*   xb     = (u16*)carve((size_t)N * HID * sizeof(u16));
    int*   srcS   = (int*)carve((size_t)(E + 64) * sizeof(int));
    int*   dstS   = (int*)carve((size_t)(E + 64) * sizeof(int));
    u16*   eaS    = (u16*)carve((size_t)(E + 64) * 4 * sizeof(u16));
    int*   rowptr = (int*)carve((size_t)(N + 1) * sizeof(int));
    int*   cursor = (int*)carve((size_t)N * sizeof(int));
    int*   cnt    = (int*)carve((size_t)N * sizeof(int));
    u16*   w1f    = (u16*)carve((size_t)4 * 72 * 512 * sizeof(u16)); // KT=9
    u16*   w2f    = (u16*)carve((size_t)4 * 32 * 512 * sizeof(u16)); // KT=4
    u16*   nwf    = (u16*)carve((size_t)4 * 64 * 512 * sizeof(u16)); // KT=8

    // ---- fused setup: weight swizzle + zero cnt/cursor/sums/counts ----
    {
        long long total = (long long)T1 + T2 + T3 + 2LL * N + (long long)G * HID + G;
        int blocks = (int)((total + 255) / 256);
        setup_kernel<<<blocks, 256, 0, stream>>>(ew1, ew2, nw, w1f, w2f, nwf,
                                                 cnt, cursor, sums, cnts_g, N, G);
    }

    // ---- CSR build (dst-sorted edges) ----
    hist_kernel<<<(E + 255) / 256, 256, 0, stream>>>(dstI, cnt, E);
    scan_kernel<<<1, 1024, 0, stream>>>(cnt, rowptr, N);
    scatter_kernel<<<(E + 255) / 256, 256, 0, stream>>>(
        srcI, dstI, edge_attr, rowptr, cursor, srcS, dstS, eaS, E);

    // embed + zero agg + graph counts
    embed_kernel<<<N, HID, 0, stream>>>(z, emb, xb, agg, batch, cnts_g, N);

    for (int l = 0; l < 4; ++l) {
        edge_mfma<<<(E + 63) / 64, 256, 0, stream>>>(
            xb, srcS, dstS, eaS,
            w1f + (size_t)l * 72 * 512, eb1 + (size_t)l * HID,
            w2f + (size_t)l * 32 * 512, eb2 + (size_t)l * HID,
            agg, E);
        node_mfma<<<(N + 31) / 32, 256, 0, stream>>>(
            xb, agg, nwf + (size_t)l * 64 * 512, nb + (size_t)l * HID,
            batch, sums, (l == 3) ? 1 : 0, N);
    }

    readout_kernel<<<G, HID, 0, stream>>>(sums, cnts_g, rw1, rb1, rw2, rb2, pred);
}